// Round 8
// baseline (2334.745 us; speedup 1.0000x reference)
//
#include <hip/hip_runtime.h>

typedef unsigned short u16;
typedef unsigned long long u64;
using s8v = __attribute__((ext_vector_type(8))) short;
using f4v = __attribute__((ext_vector_type(4))) float;

#define B_   32
#define N_   64
#define T_   128
#define D_   64
#define EMB_ 128
#define H_   256
#define E_   512
#define G3_  768

#define MFMA16(a, b, c) __builtin_amdgcn_mfma_f32_16x16x32_bf16(a, b, c, 0, 0, 0)
// coherent (agent-scope, cache-bypassing) access primitives — proven R7.
#define LOADC(p)    __hip_atomic_load((p), __ATOMIC_RELAXED, __HIP_MEMORY_SCOPE_AGENT)
#define STOREC(p,v) __hip_atomic_store((p), (v), __ATOMIC_RELAXED, __HIP_MEMORY_SCOPE_AGENT)

// per-wave flags, 16B-spaced dwords: rdy in [0,16K), gdn in [16K,32K)
#define RDY(m, z, wv) (gctr + ((((m) * 2 + (z)) * 8 + (wv)) << 2))
#define GDN(m, z, wv) (gctr + 4096 + ((((m) * 2 + (z)) * 8 + (wv)) << 2))

union h4u { u64 u; _Float16 h[4]; };
union s8u { s8v v; u64 q[2]; };

__device__ __forceinline__ float bf2f(u16 v) {
  union { unsigned u; float f; } x; x.u = ((unsigned)v) << 16; return x.f;
}
__device__ __forceinline__ u16 f2bf(float f) {
  union { float f; unsigned u; } x; x.f = f;
  unsigned r = x.u + 0x7fffu + ((x.u >> 16) & 1u);
  return (u16)(r >> 16);
}
// dual-mode float input load: bf=1 -> storage is bf16, bf=0 -> float32
__device__ __forceinline__ float ldin(const void* p, size_t i, int bf) {
  return bf ? bf2f(((const u16*)p)[i]) : ((const float*)p)[i];
}
__device__ __forceinline__ float clamp30(float x) {
  return fminf(30.f, fmaxf(-30.f, x));
}
__device__ __forceinline__ float sigm_f(float x) {
  return __builtin_amdgcn_rcpf(1.f + __expf(-clamp30(x)));
}
__device__ __forceinline__ float tanh_f(float x) {
  return 1.f - 2.f * __builtin_amdgcn_rcpf(1.f + __expf(2.f * clamp30(x)));
}

// 128 persistent blocks = (node 0..63) x (sibling s 0..1). 512 thr = 8 waves.
// R8: PER-WAVE dataflow. Wave w owns rows 4w..4w+3 end-to-end (gather row =
// tid>>4, ep-store row = tid>>4), and those rows are consumed ONLY by
// out-neighbors' wave w. So flags are per (node, sib, wave):
//  - producer wave w: stores its 2 u64/lane -> s_waitcnt vmcnt(0) ->
//    lane0 publishes rdy[node][s][w] = t+2.  NO block barrier on the path.
//  - consumer wave w: lane-parallel poll of in-neighbors' wave-w flags.
//  - ack (gdn) likewise per-wave, polled after the post-transpose barrier.
// Block barriers per step: 4 (pre-B, post-B, post-C, post-transpose) — only
// the true cross-wave LDS dependencies. xl is double-buffered to decouple
// fast waves' next-step prefetch from stragglers' gx reads.
__global__ __launch_bounds__(512) __attribute__((amdgpu_waves_per_eu(2, 2)))
void ggru_kernel(
    const void* __restrict__ x, const int* __restrict__ fi,
    const int* __restrict__ esrc, const int* __restrict__ edst,
    const void* __restrict__ Winit, const void* __restrict__ binit,
    const void* __restrict__ Wg, const void* __restrict__ bg,
    const void* __restrict__ Wih, const void* __restrict__ Whh,
    const void* __restrict__ bih, const void* __restrict__ bhh,
    const void* __restrict__ Wlast, const void* __restrict__ blast,
    float* __restrict__ out, int* __restrict__ gctr,
    _Float16* __restrict__ ep)
{
  const int node = blockIdx.x >> 1;
  const int s    = blockIdx.x & 1;
  const int tid  = threadIdx.x;
  const int w    = tid >> 6;            // wave 0..7
  const int lane = tid & 63;
  const int quad = lane >> 4;
  const int c    = lane & 15;

  __shared__ short sEdge[E_ + 2];
  __shared__ short sOut[E_ + 2];
  __shared__ int   sCnt, sCntO;
  __shared__ int   sFi[32];
  __shared__ __align__(16) u16 xl[2][32][72];  // x tile, double-buffered
  __shared__ __align__(16) u16 aggl[32][136];  // GCN aggregate / D-transpose
  __shared__ __align__(16) u16 gelF[32][264];  // FULL ge (528B rows)
  __shared__ __align__(16) u16 hl[32][136];    // own 128 h-cols

  // ---- runtime dtype probe (bf16 vs f32 storage), proven R3 ----
  int plaus = 0;
  {
    const u16* q = (const u16*)Wg;
#pragma unroll 8
    for (int i = 0; i < 512; ++i) {
      float a = fabsf(bf2f(q[i]));
      plaus += (a > 1e-4f && a < 0.3f) ? 1 : 0;
    }
  }
  const int bf = (plaus >= 450) ? 1 : 0;

  if (tid == 0) { sCnt = 0; sCntO = 0; }
  if (tid < 32) sFi[tid] = fi[tid] - 1;
  __syncthreads();
  if (edst[tid] == node) {            // in-edges: E_ == 512 == blockDim
    int q = atomicAdd(&sCnt, 1);
    sEdge[q] = (short)esrc[tid];
  }
  if (esrc[tid] == node) {            // out-edges
    int q = atomicAdd(&sCntO, 1);
    sOut[q] = (short)edst[tid];
  }
  __syncthreads();
  if (tid == 0) {
    sEdge[sCnt] = (short)node;        // append self-loop (in)
    sEdge[sCnt + 1] = (short)node;    // pipeline pad
    sOut[sCntO] = (short)node;        // self is always an out-neighbor
  }
  __syncthreads();
  const int cntS = sCnt + 1;
  const int cntO = sCntO + 1;
  const float invdeg = 1.0f / (float)cntS;

  // ---- weights -> register MFMA B-fragments (once) ----
  const int tA = 8 * s + w, tB = 8 * (1 - s) + w;
  s8v BgA[4], BgB[4];
#pragma unroll
  for (int kt = 0; kt < 4; ++kt) {
    s8v fa, fb;
#pragma unroll
    for (int j = 0; j < 8; ++j) {
      fa[j] = (short)f2bf(ldin(Wg, (size_t)(kt * 32 + quad * 8 + j) * H_ + 16 * tA + c, bf));
      fb[j] = (short)f2bf(ldin(Wg, (size_t)(kt * 32 + quad * 8 + j) * H_ + 16 * tB + c, bf));
    }
    BgA[kt] = fa; BgB[kt] = fb;
  }
  const int hcol = 128 * s + 16 * w + c;
  s8v Bih_[3][2], Bhh_[3][8];
#pragma unroll
  for (int gt = 0; gt < 3; ++gt) {
    const size_t bih_base = (size_t)node * G3_ * D_ + (size_t)(gt * H_ + hcol) * D_;
    const size_t bhh_base = (size_t)node * G3_ * H_ + (size_t)(gt * H_ + hcol) * H_;
#pragma unroll
    for (int kt = 0; kt < 2; ++kt) {
      s8v f;
#pragma unroll
      for (int j = 0; j < 8; ++j)
        f[j] = (short)f2bf(ldin(Wih, bih_base + kt * 32 + quad * 8 + j, bf));
      Bih_[gt][kt] = f;
    }
#pragma unroll
    for (int kt = 0; kt < 8; ++kt) {
      s8v f;
#pragma unroll
      for (int j = 0; j < 8; ++j)
        f[j] = (short)f2bf(ldin(Whh, bhh_base + kt * 32 + quad * 8 + j, bf));
      Bhh_[gt][kt] = f;
    }
  }
  const int ecol = 16 * w + c;
  s8v Bl_[4];
  {
    const size_t bl_base = (size_t)node * EMB_ * H_ + (size_t)ecol * H_ + 128 * s;
#pragma unroll
    for (int kt = 0; kt < 4; ++kt) {
      s8v f;
#pragma unroll
      for (int j = 0; j < 8; ++j)
        f[j] = (short)f2bf(ldin(Wlast, bl_base + kt * 32 + quad * 8 + j, bf));
      Bl_[kt] = f;
    }
  }
  const float bgcA = ldin(bg, 16 * tA + c, bf);
  const float bgcB = ldin(bg, 16 * tB + c, bf);
  float bihv[3], bhhv[3];
#pragma unroll
  for (int gt = 0; gt < 3; ++gt) {
    bihv[gt] = ldin(bih, (size_t)node * G3_ + gt * H_ + hcol, bf);
    bhhv[gt] = ldin(bhh, (size_t)node * G3_ + gt * H_ + hcol, bf);
  }
  const float blc = (s == 0) ? ldin(blast, (size_t)node * EMB_ + ecol, bf) : 0.f;

  // partial-sum buffers: ep[sib][parity][node][row][f] (fp16); u64 granularity
  const size_t NODE_SZ = (size_t)B_ * EMB_;   // 4096 fp16 = 1024 u64
  u64* __restrict__ epq = (u64*)ep;

  // ---- xl[0] <- x tile t=0 ----
  {
    const int row = tid >> 4, d0 = (tid & 15) * 4;
#pragma unroll
    for (int k = 0; k < 4; ++k)
      xl[0][row][d0 + k] = f2bf(ldin(x, ((size_t)row * N_ + node) * (T_ * D_) + d0 + k, bf));
  }
  __syncthreads();
  // ---- init: e0 = x0 @ Winit^T + binit into parity-0; s=1 writes zeros ----
  {
    const int row = tid >> 4, f0 = (tid & 15) * 8;
    u64* dst = epq + ((((size_t)(s * 2 + 0) * N_ + node) * NODE_SZ + row * EMB_ + f0) >> 2);
    if (s == 0) {
      h4u o0, o1;
#pragma unroll
      for (int ff = 0; ff < 8; ++ff) {
        const int f = f0 + ff;
        float acc = ldin(binit, (size_t)node * EMB_ + f, bf);
        const size_t wb = ((size_t)node * EMB_ + f) * D_;
#pragma unroll 8
        for (int d = 0; d < D_; ++d) acc += bf2f(xl[0][row][d]) * ldin(Winit, wb + d, bf);
        if (ff < 4) o0.h[ff] = (_Float16)acc; else o1.h[ff - 4] = (_Float16)acc;
      }
      STOREC(dst, o0.u); STOREC(dst + 1, o1.u);
    } else {
      STOREC(dst, 0ull); STOREC(dst + 1, 0ull);
    }
  }
  __syncthreads();   // vmcnt(0) drain: init stores complete at coherent point
  if (tid < 8)       // publish init production per wave (rdy = 1)
    STOREC(RDY(node, s, tid), 1);

  // ---- gx accs for t=0 ----
  f4v gxa[2][3];
#pragma unroll
  for (int rh = 0; rh < 2; ++rh)
#pragma unroll
    for (int g = 0; g < 3; ++g) gxa[rh][g] = (f4v){0.f, 0.f, 0.f, 0.f};
#pragma unroll
  for (int rh = 0; rh < 2; ++rh)
#pragma unroll
    for (int kt = 0; kt < 2; ++kt) {
      s8v a = *(const s8v*)&xl[0][16 * rh + c][kt * 32 + quad * 8];
      gxa[rh][0] = MFMA16(a, Bih_[0][kt], gxa[rh][0]);
      gxa[rh][1] = MFMA16(a, Bih_[1][kt], gxa[rh][1]);
      gxa[rh][2] = MFMA16(a, Bih_[2][kt], gxa[rh][2]);
    }

#pragma unroll 1
  for (int t = 0; t <= T_; ++t) {
    // ---- per-wave in-wait: in-neighbors' wave-w flags >= t+1 ----
    {
      const int tgt = t + 1;
      for (;;) {
        int ok = 1;
        for (int i = lane; i < 2 * cntS; i += 64) {
          const int m = (int)sEdge[i >> 1];
          if (LOADC(RDY(m, i & 1, w)) < tgt) ok = 0;
        }
        if (__all(ok)) break;
        __builtin_amdgcn_s_sleep(1);
      }
    }
    const int par = t & 1;

    // ---- out rows produced at step t-1 (per-thread, own wave rows) ----
    if (s == 0 && t >= 1) {
      const int row = tid >> 4, f0 = (tid & 15) * 8;
      if (sFi[row] == t - 1) {
        const u64* p0 = epq + ((((size_t)(0 * 2 + par) * N_ + node) * NODE_SZ + row * EMB_ + f0) >> 2);
        const u64* p1 = epq + ((((size_t)(1 * 2 + par) * N_ + node) * NODE_SZ + row * EMB_ + f0) >> 2);
        h4u a0, a1, b0, b1;
        a0.u = LOADC((u64*)p0); a1.u = LOADC((u64*)p0 + 1);
        b0.u = LOADC((u64*)p1); b1.u = LOADC((u64*)p1 + 1);
#pragma unroll
        for (int k = 0; k < 4; ++k) {
          out[(size_t)row * (N_ * EMB_) + node * EMB_ + f0 + k] =
              tanh_f((float)a0.h[k] + (float)b0.h[k]);
          out[(size_t)row * (N_ * EMB_) + node * EMB_ + f0 + 4 + k] =
              tanh_f((float)a1.h[k] + (float)b1.h[k]);
        }
      }
    }
    if (t == T_) break;

    // ---- phase A (per-wave): x_{t+1} prefetch + GCN gather of own rows ----
    if (t + 1 < T_) {
      const int row = tid >> 4, d0 = (tid & 15) * 4;
#pragma unroll
      for (int k = 0; k < 4; ++k)
        xl[(t + 1) & 1][row][d0 + k] =
            f2bf(ldin(x, ((size_t)row * N_ + node) * (T_ * D_) + (size_t)(t + 1) * D_ + d0 + k, bf));
    }
    {
      const int row = tid >> 4, f0 = (tid & 15) * 8;
      u64* b0 = epq + ((((size_t)(0 * 2 + par) * N_) * NODE_SZ + row * EMB_ + f0) >> 2);
      u64* b1 = epq + ((((size_t)(1 * 2 + par) * N_) * NODE_SZ + row * EMB_ + f0) >> 2);
      float acc[8];
#pragma unroll
      for (int k = 0; k < 8; ++k) acc[k] = 0.f;
      size_t so = (size_t)(int)sEdge[0] * (NODE_SZ >> 2);
      u64 A0 = LOADC(b0 + so), A1 = LOADC(b0 + so + 1);
      u64 C0 = LOADC(b1 + so), C1 = LOADC(b1 + so + 1);
      if (t == 0) {  // e0 is NOT tanh'd in the reference
        for (int i = 0; i < cntS; ++i) {
          size_t sn = (size_t)(int)sEdge[i + 1] * (NODE_SZ >> 2);
          u64 nA0 = LOADC(b0 + sn), nA1 = LOADC(b0 + sn + 1);
          u64 nC0 = LOADC(b1 + sn), nC1 = LOADC(b1 + sn + 1);
          h4u a0, a1, c0, c1; a0.u = A0; a1.u = A1; c0.u = C0; c1.u = C1;
#pragma unroll
          for (int k = 0; k < 4; ++k) {
            acc[k]     += (float)a0.h[k] + (float)c0.h[k];
            acc[4 + k] += (float)a1.h[k] + (float)c1.h[k];
          }
          A0 = nA0; A1 = nA1; C0 = nC0; C1 = nC1;
        }
      } else {
        for (int i = 0; i < cntS; ++i) {
          size_t sn = (size_t)(int)sEdge[i + 1] * (NODE_SZ >> 2);
          u64 nA0 = LOADC(b0 + sn), nA1 = LOADC(b0 + sn + 1);
          u64 nC0 = LOADC(b1 + sn), nC1 = LOADC(b1 + sn + 1);
          h4u a0, a1, c0, c1; a0.u = A0; a1.u = A1; c0.u = C0; c1.u = C1;
#pragma unroll
          for (int k = 0; k < 4; ++k) {
            acc[k]     += tanh_f((float)a0.h[k] + (float)c0.h[k]);
            acc[4 + k] += tanh_f((float)a1.h[k] + (float)c1.h[k]);
          }
          A0 = nA0; A1 = nA1; C0 = nC0; C1 = nC1;
        }
      }
      s8v pk;
#pragma unroll
      for (int k = 0; k < 8; ++k) pk[k] = (short)f2bf(acc[k] * invdeg);
      *(s8v*)&aggl[row][f0] = pk;
    }
    // per-wave ack publish: this wave finished reading parity `par` rows
    asm volatile("s_waitcnt vmcnt(0)" ::: "memory");
    if (lane == 0) STOREC(GDN(node, s, w), t + 1);
    __syncthreads();   // pre-B: all gather rows in aggl

    // ---- phase B: full ge = tanh(agg @ Wg + bg); wave -> tiles tA, tB ----
    float gevA[2][4];
#pragma unroll
    for (int rh = 0; rh < 2; ++rh) {
      s8v a[4];
#pragma unroll
      for (int kt = 0; kt < 4; ++kt) a[kt] = *(const s8v*)&aggl[16 * rh + c][kt * 32 + quad * 8];
      f4v accA = {0.f, 0.f, 0.f, 0.f}, accB = {0.f, 0.f, 0.f, 0.f};
#pragma unroll
      for (int kt = 0; kt < 4; ++kt) {
        accA = MFMA16(a[kt], BgA[kt], accA);
        accB = MFMA16(a[kt], BgB[kt], accB);
      }
#pragma unroll
      for (int i = 0; i < 4; ++i) {
        float vA = tanh_f(accA[i] + bgcA);
        float vB = tanh_f(accB[i] + bgcB);
        gevA[rh][i] = vA;
        gelF[16 * rh + quad * 4 + i][16 * tA + c] = f2bf(vA);
        gelF[16 * rh + quad * 4 + i][16 * tB + c] = f2bf(vB);
      }
    }
    __syncthreads();   // post-B

    // ---- phase C: GRU gates (gx precomputed; add gh contributions) ----
#pragma unroll
    for (int rh = 0; rh < 2; ++rh) {
      f4v aR = gxa[rh][0], aZ = gxa[rh][1], aXn = gxa[rh][2];
      f4v aHn = {0.f, 0.f, 0.f, 0.f};
#pragma unroll
      for (int kt = 0; kt < 8; ++kt) {
        s8v a = *(const s8v*)&gelF[16 * rh + c][kt * 32 + quad * 8];
        aR  = MFMA16(a, Bhh_[0][kt], aR);
        aZ  = MFMA16(a, Bhh_[1][kt], aZ);
        aHn = MFMA16(a, Bhh_[2][kt], aHn);
      }
#pragma unroll
      for (int i = 0; i < 4; ++i) {
        float r_ = sigm_f(aR[i] + bihv[0] + bhhv[0]);
        float z_ = sigm_f(aZ[i] + bihv[1] + bhhv[1]);
        float ng = tanh_f(aXn[i] + bihv[2] + r_ * (aHn[i] + bhhv[2]));
        float h  = (1.f - z_) * ng + z_ * gevA[rh][i];
        hl[16 * rh + quad * 4 + i][16 * w + c] = f2bf(h);
      }
    }
    __syncthreads();   // post-C

    // ---- phase D: PARTIAL e_new over own K=128 h-cols (+bias if s==0).
    //      MFMA -> LDS transpose (aggl) -> per-wave ack-wait -> 2 u64 stores
    //      of own rows -> per-wave rdy publish. ----
#pragma unroll
    for (int rh = 0; rh < 2; ++rh) {
      f4v aE = {0.f, 0.f, 0.f, 0.f};
#pragma unroll
      for (int kt = 0; kt < 4; ++kt) {
        s8v a = *(const s8v*)&hl[16 * rh + c][kt * 32 + quad * 8];
        aE = MFMA16(a, Bl_[kt], aE);
      }
#pragma unroll
      for (int i = 0; i < 4; ++i) {
        const int row = 16 * rh + quad * 4 + i;
        union { _Float16 h; u16 u; } cv;
        cv.h = (_Float16)(aE[i] + blc);
        aggl[row][ecol] = cv.u;
      }
    }
    __syncthreads();   // post-transpose

    // per-wave ack-wait: out-neighbors' wave-w finished gather t-1
    if (t > 0) {
      const int tgt = t;
      for (;;) {
        int ok = 1;
        for (int i = lane; i < 2 * cntO; i += 64) {
          const int m = (int)sOut[i >> 1];
          if (LOADC(GDN(m, i & 1, w)) < tgt) ok = 0;
        }
        if (__all(ok)) break;
        __builtin_amdgcn_s_sleep(1);
      }
    }
    {
      const int row = tid >> 4, f0 = (tid & 15) * 8;
      s8u cv; cv.v = *(const s8v*)&aggl[row][f0];
      u64* eo = epq + ((((size_t)(s * 2 + ((t + 1) & 1)) * N_ + node) * NODE_SZ + row * EMB_ + f0) >> 2);
      STOREC(eo, cv.q[0]); STOREC(eo + 1, cv.q[1]);
    }
    asm volatile("s_waitcnt vmcnt(0)" ::: "memory");  // this wave's stores acked
    if (lane == 0) STOREC(RDY(node, s, w), t + 2);    // publish per-wave

    // ---- gx(t+1) precompute (xl[(t+1)&1], cross-wave reads of A-writes
    //      separated by pre-B barrier; next-step A writes the OTHER slot) ----
    if (t + 1 < T_) {
#pragma unroll
      for (int rh = 0; rh < 2; ++rh) {
#pragma unroll
        for (int g = 0; g < 3; ++g) gxa[rh][g] = (f4v){0.f, 0.f, 0.f, 0.f};
#pragma unroll
        for (int kt = 0; kt < 2; ++kt) {
          s8v a = *(const s8v*)&xl[(t + 1) & 1][16 * rh + c][kt * 32 + quad * 8];
          gxa[rh][0] = MFMA16(a, Bih_[0][kt], gxa[rh][0]);
          gxa[rh][1] = MFMA16(a, Bih_[1][kt], gxa[rh][1]);
          gxa[rh][2] = MFMA16(a, Bih_[2][kt], gxa[rh][2]);
        }
      }
    }
  }
}

extern "C" void kernel_launch(void* const* d_in, const int* in_sizes, int n_in,
                              void* d_out, int out_size, void* d_ws, size_t ws_size,
                              hipStream_t stream) {
  const void* x     = d_in[0];
  const int*  fi    = (const int*)d_in[1];
  const int*  esrc  = (const int*)d_in[2];
  const int*  edst  = (const int*)d_in[3];
  const void* Winit = d_in[4];
  const void* binit = d_in[5];
  const void* Wg    = d_in[6];
  const void* bg    = d_in[7];
  const void* Wih   = d_in[8];
  const void* Whh   = d_in[9];
  const void* bih   = d_in[10];
  const void* bhh   = d_in[11];
  const void* Wlast = d_in[12];
  const void* blast = d_in[13];

  // d_ws: [0,32K) per-wave dataflow flags (rdy [0,16K), gdn [16K,32K), zeroed);
  // then partial buffers ep[sib 2][parity 2][N][B][EMB] fp16 = 4 MB
  int*      gctr = (int*)d_ws;
  _Float16* ep   = (_Float16*)((char*)d_ws + 32768);
  hipMemsetAsync(d_ws, 0, 32768, stream);

  ggru_kernel<<<128, 512, 0, stream>>>(
      x, fi, esrc, edst, Winit, binit, Wg, bg, Wih, Whh, bih, bhh,
      Wlast, blast, (float*)d_out, gctr, ep);
}

// Round 10
// 2143.597 us; speedup vs baseline: 1.0892x; 1.0892x over previous
//
#include <hip/hip_runtime.h>

typedef unsigned short u16;
typedef unsigned long long u64;
using s8v = __attribute__((ext_vector_type(8))) short;
using f4v = __attribute__((ext_vector_type(4))) float;

#define B_   32
#define N_   64
#define T_   128
#define D_   64
#define EMB_ 128
#define H_   256
#define E_   512
#define G3_  768

#define MFMA16(a, b, c) __builtin_amdgcn_mfma_f32_16x16x32_bf16(a, b, c, 0, 0, 0)
// coherent (agent-scope, cache-bypassing) access primitives — proven R7.
#define LOADC(p)    __hip_atomic_load((p), __ATOMIC_RELAXED, __HIP_MEMORY_SCOPE_AGENT)
#define STOREC(p,v) __hip_atomic_store((p), (v), __ATOMIC_RELAXED, __HIP_MEMORY_SCOPE_AGENT)

union h4u { u64 u; _Float16 h[4]; };
union s8u { s8v v; u64 q[2]; };

__device__ __forceinline__ float bf2f(u16 v) {
  union { unsigned u; float f; } x; x.u = ((unsigned)v) << 16; return x.f;
}
__device__ __forceinline__ u16 f2bf(float f) {
  union { float f; unsigned u; } x; x.f = f;
  unsigned r = x.u + 0x7fffu + ((x.u >> 16) & 1u);
  return (u16)(r >> 16);
}
// dual-mode float input load: bf=1 -> storage is bf16, bf=0 -> float32
__device__ __forceinline__ float ldin(const void* p, size_t i, int bf) {
  return bf ? bf2f(((const u16*)p)[i]) : ((const float*)p)[i];
}
__device__ __forceinline__ float clamp30(float x) {
  return fminf(30.f, fmaxf(-30.f, x));
}
__device__ __forceinline__ float sigm_f(float x) {
  return __builtin_amdgcn_rcpf(1.f + __expf(-clamp30(x)));
}
__device__ __forceinline__ float tanh_f(float x) {
  return 1.f - 2.f * __builtin_amdgcn_rcpf(1.f + __expf(2.f * clamp30(x)));
}

// 128 persistent blocks = (node 0..63) x (sibling s 0..1). 512 thr = 8 waves.
// R10 == R9 resubmit (container failure, no data). R9 = R7 structure
// (fence-free coherent dataflow, block-level flags — 1880us proven) +
// 4-wide grouped gather: issue all 16 u64 coherent loads of 4 edges
// back-to-back (32 VGPR in flight, half of R4's spilling footprint), one
// latency exposure per group instead of one per edge. 9 round trips -> 3.
// R4/R5's null results were measured in the fence-era regime (masked);
// this is the first fence-free test of gather batching.
__global__ __launch_bounds__(512) __attribute__((amdgpu_waves_per_eu(2, 2)))
void ggru_kernel(
    const void* __restrict__ x, const int* __restrict__ fi,
    const int* __restrict__ esrc, const int* __restrict__ edst,
    const void* __restrict__ Winit, const void* __restrict__ binit,
    const void* __restrict__ Wg, const void* __restrict__ bg,
    const void* __restrict__ Wih, const void* __restrict__ Whh,
    const void* __restrict__ bih, const void* __restrict__ bhh,
    const void* __restrict__ Wlast, const void* __restrict__ blast,
    float* __restrict__ out, int* __restrict__ gctr,
    _Float16* __restrict__ ep)
{
  const int node = blockIdx.x >> 1;
  const int s    = blockIdx.x & 1;
  const int tid  = threadIdx.x;
  const int w    = tid >> 6;            // wave 0..7
  const int lane = tid & 63;
  const int quad = lane >> 4;
  const int c    = lane & 15;

  // flag arrays: rdy at gctr[0..511], gdone at gctr[512..1023]
  int* __restrict__ rdy = gctr;
  int* __restrict__ gdn = gctr + 512;

  __shared__ short sEdge[E_ + 4];
  __shared__ short sOut[E_ + 2];
  __shared__ int   sCnt, sCntO;
  __shared__ int   sFi[32];
  __shared__ __align__(16) u16 xl[32][72];     // x_t tile (stride 144B)
  __shared__ __align__(16) u16 aggl[32][136];  // GCN aggregate / D-transpose
  __shared__ __align__(16) u16 gelF[32][264];  // FULL ge (528B rows)
  __shared__ __align__(16) u16 hl[32][136];    // own 128 h-cols

  // ---- runtime dtype probe (bf16 vs f32 storage), proven R3 ----
  int plaus = 0;
  {
    const u16* q = (const u16*)Wg;
#pragma unroll 8
    for (int i = 0; i < 512; ++i) {
      float a = fabsf(bf2f(q[i]));
      plaus += (a > 1e-4f && a < 0.3f) ? 1 : 0;
    }
  }
  const int bf = (plaus >= 450) ? 1 : 0;

  // zero-fill edge list so over-issued group loads hit valid memory (node 0)
  sEdge[tid] = 0;
  if (tid < 4) sEdge[E_ + tid] = 0;
  if (tid == 0) { sCnt = 0; sCntO = 0; }
  if (tid < 32) sFi[tid] = fi[tid] - 1;
  __syncthreads();
  if (edst[tid] == node) {            // in-edges: E_ == 512 == blockDim
    int q = atomicAdd(&sCnt, 1);
    sEdge[q] = (short)esrc[tid];
  }
  if (esrc[tid] == node) {            // out-edges
    int q = atomicAdd(&sCntO, 1);
    sOut[q] = (short)edst[tid];
  }
  __syncthreads();
  if (tid == 0) {
    sEdge[sCnt] = (short)node;        // append self-loop (in)
    sOut[sCntO] = (short)node;        // self is always an out-neighbor
  }
  __syncthreads();
  const int cntS = sCnt + 1;
  const int cntO = sCntO + 1;
  const float invdeg = 1.0f / (float)cntS;

  // ---- weights -> register MFMA B-fragments (once) ----
  const int tA = 8 * s + w, tB = 8 * (1 - s) + w;
  s8v BgA[4], BgB[4];
#pragma unroll
  for (int kt = 0; kt < 4; ++kt) {
    s8v fa, fb;
#pragma unroll
    for (int j = 0; j < 8; ++j) {
      fa[j] = (short)f2bf(ldin(Wg, (size_t)(kt * 32 + quad * 8 + j) * H_ + 16 * tA + c, bf));
      fb[j] = (short)f2bf(ldin(Wg, (size_t)(kt * 32 + quad * 8 + j) * H_ + 16 * tB + c, bf));
    }
    BgA[kt] = fa; BgB[kt] = fb;
  }
  const int hcol = 128 * s + 16 * w + c;
  s8v Bih_[3][2], Bhh_[3][8];
#pragma unroll
  for (int gt = 0; gt < 3; ++gt) {
    const size_t bih_base = (size_t)node * G3_ * D_ + (size_t)(gt * H_ + hcol) * D_;
    const size_t bhh_base = (size_t)node * G3_ * H_ + (size_t)(gt * H_ + hcol) * H_;
#pragma unroll
    for (int kt = 0; kt < 2; ++kt) {
      s8v f;
#pragma unroll
      for (int j = 0; j < 8; ++j)
        f[j] = (short)f2bf(ldin(Wih, bih_base + kt * 32 + quad * 8 + j, bf));
      Bih_[gt][kt] = f;
    }
#pragma unroll
    for (int kt = 0; kt < 8; ++kt) {
      s8v f;
#pragma unroll
      for (int j = 0; j < 8; ++j)
        f[j] = (short)f2bf(ldin(Whh, bhh_base + kt * 32 + quad * 8 + j, bf));
      Bhh_[gt][kt] = f;
    }
  }
  const int ecol = 16 * w + c;
  s8v Bl_[4];
  {
    const size_t bl_base = (size_t)node * EMB_ * H_ + (size_t)ecol * H_ + 128 * s;
#pragma unroll
    for (int kt = 0; kt < 4; ++kt) {
      s8v f;
#pragma unroll
      for (int j = 0; j < 8; ++j)
        f[j] = (short)f2bf(ldin(Wlast, bl_base + kt * 32 + quad * 8 + j, bf));
      Bl_[kt] = f;
    }
  }
  const float bgcA = ldin(bg, 16 * tA + c, bf);
  const float bgcB = ldin(bg, 16 * tB + c, bf);
  float bihv[3], bhhv[3];
#pragma unroll
  for (int gt = 0; gt < 3; ++gt) {
    bihv[gt] = ldin(bih, (size_t)node * G3_ + gt * H_ + hcol, bf);
    bhhv[gt] = ldin(bhh, (size_t)node * G3_ + gt * H_ + hcol, bf);
  }
  const float blc = (s == 0) ? ldin(blast, (size_t)node * EMB_ + ecol, bf) : 0.f;

  // partial-sum buffers: ep[sib][parity][node][row][f] (fp16); u64 granularity
  const size_t NODE_SZ = (size_t)B_ * EMB_;   // 4096 fp16 = 1024 u64
  u64* __restrict__ epq = (u64*)ep;

  // ---- xl <- x tile t=0 ----
  {
    const int row = tid >> 4, d0 = (tid & 15) * 4;
#pragma unroll
    for (int k = 0; k < 4; ++k)
      xl[row][d0 + k] = f2bf(ldin(x, ((size_t)row * N_ + node) * (T_ * D_) + d0 + k, bf));
  }
  __syncthreads();
  // ---- init: e0 = x0 @ Winit^T + binit into parity-0; s=1 writes zeros ----
  {
    const int row = tid >> 4, f0 = (tid & 15) * 8;
    u64* dst = epq + ((((size_t)(s * 2 + 0) * N_ + node) * NODE_SZ + row * EMB_ + f0) >> 2);
    if (s == 0) {
      h4u o0, o1;
#pragma unroll
      for (int ff = 0; ff < 8; ++ff) {
        const int f = f0 + ff;
        float acc = ldin(binit, (size_t)node * EMB_ + f, bf);
        const size_t wb = ((size_t)node * EMB_ + f) * D_;
#pragma unroll 8
        for (int d = 0; d < D_; ++d) acc += bf2f(xl[row][d]) * ldin(Winit, wb + d, bf);
        if (ff < 4) o0.h[ff] = (_Float16)acc; else o1.h[ff - 4] = (_Float16)acc;
      }
      STOREC(dst, o0.u); STOREC(dst + 1, o1.u);
    } else {
      STOREC(dst, 0ull); STOREC(dst + 1, 0ull);
    }
  }
  __syncthreads();   // vmcnt(0) drain: init stores complete at coherent point
  if (tid == 0)      // publish init production (rdy = 1), no fence needed
    STOREC(&rdy[node * 8 + s * 4], 1);

  // ---- gx accs for t=0 (register-resident across the wait) ----
  f4v gxa[2][3];
#pragma unroll
  for (int rh = 0; rh < 2; ++rh)
#pragma unroll
    for (int g = 0; g < 3; ++g) gxa[rh][g] = (f4v){0.f, 0.f, 0.f, 0.f};
#pragma unroll
  for (int rh = 0; rh < 2; ++rh)
#pragma unroll
    for (int kt = 0; kt < 2; ++kt) {
      s8v a = *(const s8v*)&xl[16 * rh + c][kt * 32 + quad * 8];
      gxa[rh][0] = MFMA16(a, Bih_[0][kt], gxa[rh][0]);
      gxa[rh][1] = MFMA16(a, Bih_[1][kt], gxa[rh][1]);
      gxa[rh][2] = MFMA16(a, Bih_[2][kt], gxa[rh][2]);
    }

#pragma unroll 1
  for (int t = 0; t <= T_; ++t) {
    // ---- in-wait: all in-neighbor pairs have rdy >= t+1 ----
    {
      const int tgt = t + 1;
      if (w == 0) {
        for (;;) {
          int ok = 1;
          for (int i = lane; i < cntS; i += 64) {
            const int m = (int)sEdge[i];
            if (LOADC(&rdy[m * 8]) < tgt || LOADC(&rdy[m * 8 + 4]) < tgt) ok = 0;
          }
          if (__all(ok)) break;
          __builtin_amdgcn_s_sleep(2);
        }
      }
      __syncthreads();
    }
    const int par = t & 1;

    // ---- out rows produced at step t-1 (e_new = tanh(p0+p1)) ----
    if (s == 0 && t >= 1) {
      const int row = tid >> 4, f0 = (tid & 15) * 8;
      if (sFi[row] == t - 1) {
        const u64* p0 = epq + ((((size_t)(0 * 2 + par) * N_ + node) * NODE_SZ + row * EMB_ + f0) >> 2);
        const u64* p1 = epq + ((((size_t)(1 * 2 + par) * N_ + node) * NODE_SZ + row * EMB_ + f0) >> 2);
        h4u a0, a1, b0, b1;
        a0.u = LOADC((u64*)p0); a1.u = LOADC((u64*)p0 + 1);
        b0.u = LOADC((u64*)p1); b1.u = LOADC((u64*)p1 + 1);
#pragma unroll
        for (int k = 0; k < 4; ++k) {
          out[(size_t)row * (N_ * EMB_) + node * EMB_ + f0 + k] =
              tanh_f((float)a0.h[k] + (float)b0.h[k]);
          out[(size_t)row * (N_ * EMB_) + node * EMB_ + f0 + 4 + k] =
              tanh_f((float)a1.h[k] + (float)b1.h[k]);
        }
      }
    }
    if (t == T_) break;

    // ---- phase A: x_{t+1} prefetch + GCN gather (4-wide load groups) ----
    if (t + 1 < T_) {
      const int row = tid >> 4, d0 = (tid & 15) * 4;
#pragma unroll
      for (int k = 0; k < 4; ++k)
        xl[row][d0 + k] = f2bf(ldin(x, ((size_t)row * N_ + node) * (T_ * D_) + (size_t)(t + 1) * D_ + d0 + k, bf));
    }
    {
      const int row = tid >> 4, f0 = (tid & 15) * 8;
      u64* b0 = epq + ((((size_t)(0 * 2 + par) * N_) * NODE_SZ + row * EMB_ + f0) >> 2);
      u64* b1 = epq + ((((size_t)(1 * 2 + par) * N_) * NODE_SZ + row * EMB_ + f0) >> 2);
      float acc[8];
#pragma unroll
      for (int k = 0; k < 8; ++k) acc[k] = 0.f;
      const int ng = (cntS + 3) >> 2;
#pragma unroll 1
      for (int g = 0; g < ng; ++g) {
        // issue all 16 u64 loads of the group back-to-back (one exposure)
        u64 A0[4], A1[4], C0[4], C1[4];
#pragma unroll
        for (int j = 0; j < 4; ++j) {
          const size_t so = (size_t)(int)sEdge[4 * g + j] * (NODE_SZ >> 2);
          A0[j] = LOADC(b0 + so); A1[j] = LOADC(b0 + so + 1);
          C0[j] = LOADC(b1 + so); C1[j] = LOADC(b1 + so + 1);
        }
        if (t == 0) {  // e0 is NOT tanh'd in the reference
#pragma unroll
          for (int j = 0; j < 4; ++j) {
            if (4 * g + j < cntS) {      // wave-uniform branch
              h4u a0, a1, c0, c1;
              a0.u = A0[j]; a1.u = A1[j]; c0.u = C0[j]; c1.u = C1[j];
#pragma unroll
              for (int k = 0; k < 4; ++k) {
                acc[k]     += (float)a0.h[k] + (float)c0.h[k];
                acc[4 + k] += (float)a1.h[k] + (float)c1.h[k];
              }
            }
          }
        } else {
#pragma unroll
          for (int j = 0; j < 4; ++j) {
            if (4 * g + j < cntS) {      // wave-uniform branch
              h4u a0, a1, c0, c1;
              a0.u = A0[j]; a1.u = A1[j]; c0.u = C0[j]; c1.u = C1[j];
#pragma unroll
              for (int k = 0; k < 4; ++k) {
                acc[k]     += tanh_f((float)a0.h[k] + (float)c0.h[k]);
                acc[4 + k] += tanh_f((float)a1.h[k] + (float)c1.h[k]);
              }
            }
          }
        }
      }
      s8v pk;
#pragma unroll
      for (int k = 0; k < 8; ++k) pk[k] = (short)f2bf(acc[k] * invdeg);
      *(s8v*)&aggl[row][f0] = pk;
    }
    __syncthreads();   // gather loads drained (pre-barrier waitcnt)
    if (tid == 0)      // ack: this block finished reading parity `par`
      STOREC(&gdn[node * 8 + s * 4], t + 1);

    // ---- phase B: full ge = tanh(agg @ Wg + bg); wave -> tiles tA, tB ----
    float gevA[2][4];
#pragma unroll
    for (int rh = 0; rh < 2; ++rh) {
      s8v a[4];
#pragma unroll
      for (int kt = 0; kt < 4; ++kt) a[kt] = *(const s8v*)&aggl[16 * rh + c][kt * 32 + quad * 8];
      f4v accA = {0.f, 0.f, 0.f, 0.f}, accB = {0.f, 0.f, 0.f, 0.f};
#pragma unroll
      for (int kt = 0; kt < 4; ++kt) {
        accA = MFMA16(a[kt], BgA[kt], accA);
        accB = MFMA16(a[kt], BgB[kt], accB);
      }
#pragma unroll
      for (int i = 0; i < 4; ++i) {
        float vA = tanh_f(accA[i] + bgcA);
        float vB = tanh_f(accB[i] + bgcB);
        gevA[rh][i] = vA;
        gelF[16 * rh + quad * 4 + i][16 * tA + c] = f2bf(vA);
        gelF[16 * rh + quad * 4 + i][16 * tB + c] = f2bf(vB);
      }
    }
    __syncthreads();

    // ---- phase C: GRU gates (gx precomputed; add gh contributions) ----
#pragma unroll
    for (int rh = 0; rh < 2; ++rh) {
      f4v aR = gxa[rh][0], aZ = gxa[rh][1], aXn = gxa[rh][2];
      f4v aHn = {0.f, 0.f, 0.f, 0.f};
#pragma unroll
      for (int kt = 0; kt < 8; ++kt) {
        s8v a = *(const s8v*)&gelF[16 * rh + c][kt * 32 + quad * 8];
        aR  = MFMA16(a, Bhh_[0][kt], aR);
        aZ  = MFMA16(a, Bhh_[1][kt], aZ);
        aHn = MFMA16(a, Bhh_[2][kt], aHn);
      }
#pragma unroll
      for (int i = 0; i < 4; ++i) {
        float r_ = sigm_f(aR[i] + bihv[0] + bhhv[0]);
        float z_ = sigm_f(aZ[i] + bihv[1] + bhhv[1]);
        float ng = tanh_f(aXn[i] + bihv[2] + r_ * (aHn[i] + bhhv[2]));
        float h  = (1.f - z_) * ng + z_ * gevA[rh][i];
        hl[16 * rh + quad * 4 + i][16 * w + c] = f2bf(h);
      }
    }
    __syncthreads();

    // ---- ack-wait: out-neighbor pairs finished gather t-1 (gdone >= t) ----
    {
      const int tgt = t;
      if (tgt > 0) {
        if (w == 0) {
          for (;;) {
            int ok = 1;
            for (int i = lane; i < cntO; i += 64) {
              const int m = (int)sOut[i];
              if (LOADC(&gdn[m * 8]) < tgt || LOADC(&gdn[m * 8 + 4]) < tgt) ok = 0;
            }
            if (__all(ok)) break;
            __builtin_amdgcn_s_sleep(2);
          }
        }
        __syncthreads();   // no wave stores to ep before the license
      }
    }

    // ---- phase D: PARTIAL e_new over own K=128 h-cols (+bias if s==0).
    //      Scattered column results -> LDS transpose (aggl, free here) ->
    //      2 contiguous coherent u64 stores per thread. ----
#pragma unroll
    for (int rh = 0; rh < 2; ++rh) {
      f4v aE = {0.f, 0.f, 0.f, 0.f};
#pragma unroll
      for (int kt = 0; kt < 4; ++kt) {
        s8v a = *(const s8v*)&hl[16 * rh + c][kt * 32 + quad * 8];
        aE = MFMA16(a, Bl_[kt], aE);
      }
#pragma unroll
      for (int i = 0; i < 4; ++i) {
        const int row = 16 * rh + quad * 4 + i;
        union { _Float16 h; u16 u; } cv;
        cv.h = (_Float16)(aE[i] + blc);
        aggl[row][ecol] = cv.u;
      }
    }
    __syncthreads();
    {
      const int row = tid >> 4, f0 = (tid & 15) * 8;
      s8u cv; cv.v = *(const s8v*)&aggl[row][f0];
      u64* eo = epq + ((((size_t)(s * 2 + ((t + 1) & 1)) * N_ + node) * NODE_SZ + row * EMB_ + f0) >> 2);
      STOREC(eo, cv.q[0]); STOREC(eo + 1, cv.q[1]);
    }
    __syncthreads();     // vmcnt(0): ep stores complete at coherent point
    if (tid == 0)        // publish production for gather-step t+1 (no fence)
      STOREC(&rdy[node * 8 + s * 4], t + 2);

    // ---- gx(t+1) precompute (xl holds x_{t+1}); overlaps flag propagation ----
    if (t + 1 < T_) {
#pragma unroll
      for (int rh = 0; rh < 2; ++rh) {
#pragma unroll
        for (int g = 0; g < 3; ++g) gxa[rh][g] = (f4v){0.f, 0.f, 0.f, 0.f};
#pragma unroll
        for (int kt = 0; kt < 2; ++kt) {
          s8v a = *(const s8v*)&xl[16 * rh + c][kt * 32 + quad * 8];
          gxa[rh][0] = MFMA16(a, Bih_[0][kt], gxa[rh][0]);
          gxa[rh][1] = MFMA16(a, Bih_[1][kt], gxa[rh][1]);
          gxa[rh][2] = MFMA16(a, Bih_[2][kt], gxa[rh][2]);
        }
      }
    }
  }
}

extern "C" void kernel_launch(void* const* d_in, const int* in_sizes, int n_in,
                              void* d_out, int out_size, void* d_ws, size_t ws_size,
                              hipStream_t stream) {
  const void* x     = d_in[0];
  const int*  fi    = (const int*)d_in[1];
  const int*  esrc  = (const int*)d_in[2];
  const int*  edst  = (const int*)d_in[3];
  const void* Winit = d_in[4];
  const void* binit = d_in[5];
  const void* Wg    = d_in[6];
  const void* bg    = d_in[7];
  const void* Wih   = d_in[8];
  const void* Whh   = d_in[9];
  const void* bih   = d_in[10];
  const void* bhh   = d_in[11];
  const void* Wlast = d_in[12];
  const void* blast = d_in[13];

  // d_ws: [0,4096) dataflow flags (rdy at +0, gdone at +2048, zeroed);
  // then partial buffers ep[sib 2][parity 2][N][B][EMB] fp16 = 4 MB
  int*      gctr = (int*)d_ws;
  _Float16* ep   = (_Float16*)((char*)d_ws + 4096);
  hipMemsetAsync(d_ws, 0, 4096, stream);

  ggru_kernel<<<128, 512, 0, stream>>>(
      x, fi, esrc, edst, Winit, binit, Wg, bg, Wih, Whh, bih, bhh,
      Wlast, blast, (float*)d_out, gctr, ep);
}

// Round 11
// 1861.888 us; speedup vs baseline: 1.2540x; 1.1513x over previous
//
#include <hip/hip_runtime.h>

typedef unsigned short u16;
typedef unsigned long long u64;
using s8v = __attribute__((ext_vector_type(8))) short;
using f4v = __attribute__((ext_vector_type(4))) float;
using h8v = __attribute__((ext_vector_type(8))) _Float16;

#define B_   32
#define N_   64
#define T_   128
#define D_   64
#define EMB_ 128
#define H_   256
#define E_   512
#define G3_  768

#define MFMA16(a, b, c) __builtin_amdgcn_mfma_f32_16x16x32_bf16(a, b, c, 0, 0, 0)
// coherent (agent-scope, cache-bypassing) access primitives — proven R7.
#define LOADC(p)    __hip_atomic_load((p), __ATOMIC_RELAXED, __HIP_MEMORY_SCOPE_AGENT)
#define STOREC(p,v) __hip_atomic_store((p), (v), __ATOMIC_RELAXED, __HIP_MEMORY_SCOPE_AGENT)

union h4u { u64 u; _Float16 h[4]; };
union s8u { s8v v; u64 q[2]; };

__device__ __forceinline__ float bf2f(u16 v) {
  union { unsigned u; float f; } x; x.u = ((unsigned)v) << 16; return x.f;
}
__device__ __forceinline__ u16 f2bf(float f) {
  union { float f; unsigned u; } x; x.f = f;
  unsigned r = x.u + 0x7fffu + ((x.u >> 16) & 1u);
  return (u16)(r >> 16);
}
// dual-mode float input load: bf=1 -> storage is bf16, bf=0 -> float32
__device__ __forceinline__ float ldin(const void* p, size_t i, int bf) {
  return bf ? bf2f(((const u16*)p)[i]) : ((const float*)p)[i];
}
// clampless: all args bounded by weight scale (|x| <= ~40, exp finite)
__device__ __forceinline__ float sigm_f(float x) {
  return __builtin_amdgcn_rcpf(1.f + __expf(-x));
}
__device__ __forceinline__ float tanh_f(float x) {
  return 1.f - 2.f * __builtin_amdgcn_rcpf(1.f + __expf(2.f * x));
}

// 128 persistent blocks = (node 0..63) x (sibling s 0..1). 512 thr = 8 waves.
// R11 = R7 (fence-free coherent dataflow, block flags, 2-deep pipelined
// gather — 1880us proven; R10's grouped gather regressed via node-0 LLC
// hotspot from over-issued pad loads) +
//  - 4-deep ep parity (8MB): ack target gdn >= t-2 (2 steps slack) -> the
//    per-step ack LLC poll is first-try-success and runs under wave0's
//    transpose work, OFF the serial spine; its barrier pair folds away.
//  - barriers/step 7 -> 6.
//  - clampless tanh/sigm (args bounded; saves ~170 VALU/step in gather).
__global__ __launch_bounds__(512) __attribute__((amdgpu_waves_per_eu(2, 2)))
void ggru_kernel(
    const void* __restrict__ x, const int* __restrict__ fi,
    const int* __restrict__ esrc, const int* __restrict__ edst,
    const void* __restrict__ Winit, const void* __restrict__ binit,
    const void* __restrict__ Wg, const void* __restrict__ bg,
    const void* __restrict__ Wih, const void* __restrict__ Whh,
    const void* __restrict__ bih, const void* __restrict__ bhh,
    const void* __restrict__ Wlast, const void* __restrict__ blast,
    float* __restrict__ out, int* __restrict__ gctr,
    _Float16* __restrict__ ep)
{
  const int node = blockIdx.x >> 1;
  const int s    = blockIdx.x & 1;
  const int tid  = threadIdx.x;
  const int w    = tid >> 6;            // wave 0..7
  const int lane = tid & 63;
  const int quad = lane >> 4;
  const int c    = lane & 15;

  // flag arrays: rdy at gctr[0..511], gdone at gctr[512..1023]
  int* __restrict__ rdy = gctr;
  int* __restrict__ gdn = gctr + 512;

  __shared__ short sEdge[E_ + 2];
  __shared__ short sOut[E_ + 2];
  __shared__ int   sCnt, sCntO;
  __shared__ int   sFi[32];
  __shared__ __align__(16) u16 xl[32][72];     // x_t tile (stride 144B)
  __shared__ __align__(16) u16 aggl[32][136];  // GCN aggregate / D-transpose
  __shared__ __align__(16) u16 gelF[32][264];  // FULL ge (528B rows)
  __shared__ __align__(16) u16 hl[32][136];    // own 128 h-cols

  // ---- runtime dtype probe (bf16 vs f32 storage), proven R3 ----
  int plaus = 0;
  {
    const u16* q = (const u16*)Wg;
#pragma unroll 8
    for (int i = 0; i < 512; ++i) {
      float a = fabsf(bf2f(q[i]));
      plaus += (a > 1e-4f && a < 0.3f) ? 1 : 0;
    }
  }
  const int bf = (plaus >= 450) ? 1 : 0;

  if (tid == 0) { sCnt = 0; sCntO = 0; }
  if (tid < 32) sFi[tid] = fi[tid] - 1;
  __syncthreads();
  if (edst[tid] == node) {            // in-edges: E_ == 512 == blockDim
    int q = atomicAdd(&sCnt, 1);
    sEdge[q] = (short)esrc[tid];
  }
  if (esrc[tid] == node) {            // out-edges
    int q = atomicAdd(&sCntO, 1);
    sOut[q] = (short)edst[tid];
  }
  __syncthreads();
  if (tid == 0) {
    sEdge[sCnt] = (short)node;        // append self-loop (in)
    sEdge[sCnt + 1] = (short)node;    // pipeline pad
    sOut[sCntO] = (short)node;        // self is always an out-neighbor
  }
  __syncthreads();
  const int cntS = sCnt + 1;
  const int cntO = sCntO + 1;
  const float invdeg = 1.0f / (float)cntS;

  // ---- weights -> register MFMA B-fragments (once) ----
  const int tA = 8 * s + w, tB = 8 * (1 - s) + w;
  s8v BgA[4], BgB[4];
#pragma unroll
  for (int kt = 0; kt < 4; ++kt) {
    s8v fa, fb;
#pragma unroll
    for (int j = 0; j < 8; ++j) {
      fa[j] = (short)f2bf(ldin(Wg, (size_t)(kt * 32 + quad * 8 + j) * H_ + 16 * tA + c, bf));
      fb[j] = (short)f2bf(ldin(Wg, (size_t)(kt * 32 + quad * 8 + j) * H_ + 16 * tB + c, bf));
    }
    BgA[kt] = fa; BgB[kt] = fb;
  }
  const int hcol = 128 * s + 16 * w + c;
  s8v Bih_[3][2], Bhh_[3][8];
#pragma unroll
  for (int gt = 0; gt < 3; ++gt) {
    const size_t bih_base = (size_t)node * G3_ * D_ + (size_t)(gt * H_ + hcol) * D_;
    const size_t bhh_base = (size_t)node * G3_ * H_ + (size_t)(gt * H_ + hcol) * H_;
#pragma unroll
    for (int kt = 0; kt < 2; ++kt) {
      s8v f;
#pragma unroll
      for (int j = 0; j < 8; ++j)
        f[j] = (short)f2bf(ldin(Wih, bih_base + kt * 32 + quad * 8 + j, bf));
      Bih_[gt][kt] = f;
    }
#pragma unroll
    for (int kt = 0; kt < 8; ++kt) {
      s8v f;
#pragma unroll
      for (int j = 0; j < 8; ++j)
        f[j] = (short)f2bf(ldin(Whh, bhh_base + kt * 32 + quad * 8 + j, bf));
      Bhh_[gt][kt] = f;
    }
  }
  const int ecol = 16 * w + c;
  s8v Bl_[4];
  {
    const size_t bl_base = (size_t)node * EMB_ * H_ + (size_t)ecol * H_ + 128 * s;
#pragma unroll
    for (int kt = 0; kt < 4; ++kt) {
      s8v f;
#pragma unroll
      for (int j = 0; j < 8; ++j)
        f[j] = (short)f2bf(ldin(Wlast, bl_base + kt * 32 + quad * 8 + j, bf));
      Bl_[kt] = f;
    }
  }
  const float bgcA = ldin(bg, 16 * tA + c, bf);
  const float bgcB = ldin(bg, 16 * tB + c, bf);
  float bihv[3], bhhv[3];
#pragma unroll
  for (int gt = 0; gt < 3; ++gt) {
    bihv[gt] = ldin(bih, (size_t)node * G3_ + gt * H_ + hcol, bf);
    bhhv[gt] = ldin(bhh, (size_t)node * G3_ + gt * H_ + hcol, bf);
  }
  const float blc = (s == 0) ? ldin(blast, (size_t)node * EMB_ + ecol, bf) : 0.f;

  // partial buffers: ep[sib 2][parity 4][node][row][f] (fp16); u64 granularity
  const size_t NODE_SZ = (size_t)B_ * EMB_;   // 4096 fp16 = 1024 u64
  u64* __restrict__ epq = (u64*)ep;

  // ---- xl <- x tile t=0 ----
  {
    const int row = tid >> 4, d0 = (tid & 15) * 4;
#pragma unroll
    for (int k = 0; k < 4; ++k)
      xl[row][d0 + k] = f2bf(ldin(x, ((size_t)row * N_ + node) * (T_ * D_) + d0 + k, bf));
  }
  __syncthreads();
  // ---- init: e0 = x0 @ Winit^T + binit into parity-0; s=1 writes zeros ----
  {
    const int row = tid >> 4, f0 = (tid & 15) * 8;
    u64* dst = epq + ((((size_t)(s * 4 + 0) * N_ + node) * NODE_SZ + row * EMB_ + f0) >> 2);
    if (s == 0) {
      h4u o0, o1;
#pragma unroll
      for (int ff = 0; ff < 8; ++ff) {
        const int f = f0 + ff;
        float acc = ldin(binit, (size_t)node * EMB_ + f, bf);
        const size_t wb = ((size_t)node * EMB_ + f) * D_;
#pragma unroll 8
        for (int d = 0; d < D_; ++d) acc += bf2f(xl[row][d]) * ldin(Winit, wb + d, bf);
        if (ff < 4) o0.h[ff] = (_Float16)acc; else o1.h[ff - 4] = (_Float16)acc;
      }
      STOREC(dst, o0.u); STOREC(dst + 1, o1.u);
    } else {
      STOREC(dst, 0ull); STOREC(dst + 1, 0ull);
    }
  }
  __syncthreads();   // vmcnt(0) drain: init stores complete at coherent point
  if (tid == 0)      // publish init production (rdy = 1), no fence needed
    STOREC(&rdy[node * 8 + s * 4], 1);

  // ---- gx accs for t=0 (register-resident across the wait) ----
  f4v gxa[2][3];
#pragma unroll
  for (int rh = 0; rh < 2; ++rh)
#pragma unroll
    for (int g = 0; g < 3; ++g) gxa[rh][g] = (f4v){0.f, 0.f, 0.f, 0.f};
#pragma unroll
  for (int rh = 0; rh < 2; ++rh)
#pragma unroll
    for (int kt = 0; kt < 2; ++kt) {
      s8v a = *(const s8v*)&xl[16 * rh + c][kt * 32 + quad * 8];
      gxa[rh][0] = MFMA16(a, Bih_[0][kt], gxa[rh][0]);
      gxa[rh][1] = MFMA16(a, Bih_[1][kt], gxa[rh][1]);
      gxa[rh][2] = MFMA16(a, Bih_[2][kt], gxa[rh][2]);
    }

#pragma unroll 1
  for (int t = 0; t <= T_; ++t) {
    // ---- in-wait: all in-neighbor pairs have rdy >= t+1 ----
    {
      const int tgt = t + 1;
      if (w == 0) {
        for (;;) {
          int ok = 1;
          for (int i = lane; i < cntS; i += 64) {
            const int m = (int)sEdge[i];
            if (LOADC(&rdy[m * 8]) < tgt || LOADC(&rdy[m * 8 + 4]) < tgt) ok = 0;
          }
          if (__all(ok)) break;
          __builtin_amdgcn_s_sleep(2);
        }
      }
      __syncthreads();                                  // sync 1
    }
    const int par = t & 3;

    // ---- out rows produced at step t-1 (e_new = tanh(p0+p1)) ----
    if (s == 0 && t >= 1) {
      const int row = tid >> 4, f0 = (tid & 15) * 8;
      if (sFi[row] == t - 1) {
        const u64* p0 = epq + ((((size_t)(0 * 4 + par) * N_ + node) * NODE_SZ + row * EMB_ + f0) >> 2);
        const u64* p1 = epq + ((((size_t)(1 * 4 + par) * N_ + node) * NODE_SZ + row * EMB_ + f0) >> 2);
        h4u a0, a1, b0, b1;
        a0.u = LOADC((u64*)p0); a1.u = LOADC((u64*)p0 + 1);
        b0.u = LOADC((u64*)p1); b1.u = LOADC((u64*)p1 + 1);
#pragma unroll
        for (int k = 0; k < 4; ++k) {
          out[(size_t)row * (N_ * EMB_) + node * EMB_ + f0 + k] =
              tanh_f((float)a0.h[k] + (float)b0.h[k]);
          out[(size_t)row * (N_ * EMB_) + node * EMB_ + f0 + 4 + k] =
              tanh_f((float)a1.h[k] + (float)b1.h[k]);
        }
      }
    }
    if (t == T_) break;

    // ---- phase A: x_{t+1} prefetch + GCN gather (2-deep pipelined) ----
    if (t + 1 < T_) {
      const int row = tid >> 4, d0 = (tid & 15) * 4;
#pragma unroll
      for (int k = 0; k < 4; ++k)
        xl[row][d0 + k] = f2bf(ldin(x, ((size_t)row * N_ + node) * (T_ * D_) + (size_t)(t + 1) * D_ + d0 + k, bf));
    }
    {
      const int row = tid >> 4, f0 = (tid & 15) * 8;
      u64* b0 = epq + ((((size_t)(0 * 4 + par) * N_) * NODE_SZ + row * EMB_ + f0) >> 2);
      u64* b1 = epq + ((((size_t)(1 * 4 + par) * N_) * NODE_SZ + row * EMB_ + f0) >> 2);
      float acc[8];
#pragma unroll
      for (int k = 0; k < 8; ++k) acc[k] = 0.f;
      size_t so = (size_t)(int)sEdge[0] * (NODE_SZ >> 2);
      u64 A0 = LOADC(b0 + so), A1 = LOADC(b0 + so + 1);
      u64 C0 = LOADC(b1 + so), C1 = LOADC(b1 + so + 1);
      if (t == 0) {  // e0 is NOT tanh'd in the reference
        for (int i = 0; i < cntS; ++i) {
          size_t sn = (size_t)(int)sEdge[i + 1] * (NODE_SZ >> 2);
          u64 nA0 = LOADC(b0 + sn), nA1 = LOADC(b0 + sn + 1);
          u64 nC0 = LOADC(b1 + sn), nC1 = LOADC(b1 + sn + 1);
          h4u a0, a1, c0, c1; a0.u = A0; a1.u = A1; c0.u = C0; c1.u = C1;
#pragma unroll
          for (int k = 0; k < 4; ++k) {
            acc[k]     += (float)a0.h[k] + (float)c0.h[k];
            acc[4 + k] += (float)a1.h[k] + (float)c1.h[k];
          }
          A0 = nA0; A1 = nA1; C0 = nC0; C1 = nC1;
        }
      } else {
        for (int i = 0; i < cntS; ++i) {
          size_t sn = (size_t)(int)sEdge[i + 1] * (NODE_SZ >> 2);
          u64 nA0 = LOADC(b0 + sn), nA1 = LOADC(b0 + sn + 1);
          u64 nC0 = LOADC(b1 + sn), nC1 = LOADC(b1 + sn + 1);
          h4u a0, a1, c0, c1; a0.u = A0; a1.u = A1; c0.u = C0; c1.u = C1;
#pragma unroll
          for (int k = 0; k < 4; ++k) {
            acc[k]     += tanh_f((float)a0.h[k] + (float)c0.h[k]);
            acc[4 + k] += tanh_f((float)a1.h[k] + (float)c1.h[k]);
          }
          A0 = nA0; A1 = nA1; C0 = nC0; C1 = nC1;
        }
      }
      s8v pk;
#pragma unroll
      for (int k = 0; k < 8; ++k) pk[k] = (short)f2bf(acc[k] * invdeg);
      *(s8v*)&aggl[row][f0] = pk;
    }
    __syncthreads();   // sync 2: gather loads drained (pre-barrier waitcnt)
    if (tid == 0)      // ack: this block finished reading parity `par`
      STOREC(&gdn[node * 8 + s * 4], t + 1);

    // ---- phase B: full ge = tanh(agg @ Wg + bg); wave -> tiles tA, tB ----
    float gevA[2][4];
#pragma unroll
    for (int rh = 0; rh < 2; ++rh) {
      s8v a[4];
#pragma unroll
      for (int kt = 0; kt < 4; ++kt) a[kt] = *(const s8v*)&aggl[16 * rh + c][kt * 32 + quad * 8];
      f4v accA = {0.f, 0.f, 0.f, 0.f}, accB = {0.f, 0.f, 0.f, 0.f};
#pragma unroll
      for (int kt = 0; kt < 4; ++kt) {
        accA = MFMA16(a[kt], BgA[kt], accA);
        accB = MFMA16(a[kt], BgB[kt], accB);
      }
#pragma unroll
      for (int i = 0; i < 4; ++i) {
        float vA = tanh_f(accA[i] + bgcA);
        float vB = tanh_f(accB[i] + bgcB);
        gevA[rh][i] = vA;
        gelF[16 * rh + quad * 4 + i][16 * tA + c] = f2bf(vA);
        gelF[16 * rh + quad * 4 + i][16 * tB + c] = f2bf(vB);
      }
    }
    __syncthreads();   // sync 3

    // ---- phase C: GRU gates (gx precomputed; add gh contributions) ----
#pragma unroll
    for (int rh = 0; rh < 2; ++rh) {
      f4v aR = gxa[rh][0], aZ = gxa[rh][1], aXn = gxa[rh][2];
      f4v aHn = {0.f, 0.f, 0.f, 0.f};
#pragma unroll
      for (int kt = 0; kt < 8; ++kt) {
        s8v a = *(const s8v*)&gelF[16 * rh + c][kt * 32 + quad * 8];
        aR  = MFMA16(a, Bhh_[0][kt], aR);
        aZ  = MFMA16(a, Bhh_[1][kt], aZ);
        aHn = MFMA16(a, Bhh_[2][kt], aHn);
      }
#pragma unroll
      for (int i = 0; i < 4; ++i) {
        float r_ = sigm_f(aR[i] + bihv[0] + bhhv[0]);
        float z_ = sigm_f(aZ[i] + bihv[1] + bhhv[1]);
        float ng = tanh_f(aXn[i] + bihv[2] + r_ * (aHn[i] + bhhv[2]));
        float h  = (1.f - z_) * ng + z_ * gevA[rh][i];
        hl[16 * rh + quad * 4 + i][16 * w + c] = f2bf(h);
      }
    }
    __syncthreads();   // sync 4

    // ---- phase D: MFMA over own K=128 h-cols -> LDS transpose; wave 0
    //      polls the (2-step-slack) overwrite ack under the transpose. ----
#pragma unroll
    for (int rh = 0; rh < 2; ++rh) {
      f4v aE = {0.f, 0.f, 0.f, 0.f};
#pragma unroll
      for (int kt = 0; kt < 4; ++kt) {
        s8v a = *(const s8v*)&hl[16 * rh + c][kt * 32 + quad * 8];
        aE = MFMA16(a, Bl_[kt], aE);
      }
#pragma unroll
      for (int i = 0; i < 4; ++i) {
        const int row = 16 * rh + quad * 4 + i;
        union { _Float16 h; u16 u; } cv;
        cv.h = (_Float16)(aE[i] + blc);
        aggl[row][ecol] = cv.u;
      }
    }
    // ack-wait (4-parity: target t-2, two steps of slack -> ~instant)
    if (w == 0 && t >= 3) {
      const int tgt = t - 2;
      for (;;) {
        int ok = 1;
        for (int i = lane; i < cntO; i += 64) {
          const int m = (int)sOut[i];
          if (LOADC(&gdn[m * 8]) < tgt || LOADC(&gdn[m * 8 + 4]) < tgt) ok = 0;
        }
        if (__all(ok)) break;
        __builtin_amdgcn_s_sleep(2);
      }
    }
    __syncthreads();   // sync 5: transpose visible + ack license granted
    {
      const int row = tid >> 4, f0 = (tid & 15) * 8;
      s8u cv; cv.v = *(const s8v*)&aggl[row][f0];
      u64* eo = epq + ((((size_t)(s * 4 + ((t + 1) & 3)) * N_ + node) * NODE_SZ + row * EMB_ + f0) >> 2);
      STOREC(eo, cv.q[0]); STOREC(eo + 1, cv.q[1]);
    }
    __syncthreads();   // sync 6: vmcnt(0) — ep stores complete at coherent pt
    if (tid == 0)      // publish production for gather-step t+1 (no fence)
      STOREC(&rdy[node * 8 + s * 4], t + 2);

    // ---- gx(t+1) precompute (xl holds x_{t+1}); overlaps flag propagation ----
    if (t + 1 < T_) {
#pragma unroll
      for (int rh = 0; rh < 2; ++rh) {
#pragma unroll
        for (int g = 0; g < 3; ++g) gxa[rh][g] = (f4v){0.f, 0.f, 0.f, 0.f};
#pragma unroll
        for (int kt = 0; kt < 2; ++kt) {
          s8v a = *(const s8v*)&xl[16 * rh + c][kt * 32 + quad * 8];
          gxa[rh][0] = MFMA16(a, Bih_[0][kt], gxa[rh][0]);
          gxa[rh][1] = MFMA16(a, Bih_[1][kt], gxa[rh][1]);
          gxa[rh][2] = MFMA16(a, Bih_[2][kt], gxa[rh][2]);
        }
      }
    }
  }
}

extern "C" void kernel_launch(void* const* d_in, const int* in_sizes, int n_in,
                              void* d_out, int out_size, void* d_ws, size_t ws_size,
                              hipStream_t stream) {
  const void* x     = d_in[0];
  const int*  fi    = (const int*)d_in[1];
  const int*  esrc  = (const int*)d_in[2];
  const int*  edst  = (const int*)d_in[3];
  const void* Winit = d_in[4];
  const void* binit = d_in[5];
  const void* Wg    = d_in[6];
  const void* bg    = d_in[7];
  const void* Wih   = d_in[8];
  const void* Whh   = d_in[9];
  const void* bih   = d_in[10];
  const void* bhh   = d_in[11];
  const void* Wlast = d_in[12];
  const void* blast = d_in[13];

  // d_ws: [0,4096) dataflow flags (rdy at +0, gdone at +2048, zeroed);
  // then partial buffers ep[sib 2][parity 4][N][B][EMB] fp16 = 8 MB
  int*      gctr = (int*)d_ws;
  _Float16* ep   = (_Float16*)((char*)d_ws + 4096);
  hipMemsetAsync(d_ws, 0, 4096, stream);

  ggru_kernel<<<128, 512, 0, stream>>>(
      x, fi, esrc, edst, Winit, binit, Wg, bg, Wih, Whh, bih, bhh,
      Wlast, blast, (float*)d_out, gctr, ep);
}